// Round 7
// baseline (427.946 us; speedup 1.0000x reference)
//
#include <hip/hip_runtime.h>
#include <hip/hip_bf16.h>
#include <math.h>

// Problem constants (reference: B=64, L=1024, H=64, VOCAB=64)
#define BB 64
#define LL 1024
#define HH 64

typedef float v4f __attribute__((ext_vector_type(4)));
#define F4 __builtin_elementwise_fma

// ---------------------------------------------------------------------------
// Kernel 1: per-token phase (unchanged).
// ---------------------------------------------------------------------------
__global__ __launch_bounds__(256, 1)
void token_kernel(const int* __restrict__ seq,
                  const float* __restrict__ embed_W,
                  const float* __restrict__ ff_W1, const float* __restrict__ ff_b1,
                  const float* __restrict__ ff_W2, const float* __restrict__ ff_b2,
                  const float* __restrict__ ln_g, const float* __restrict__ ln_b,
                  const float* __restrict__ kp_W, const float* __restrict__ vp_W,
                  const float* __restrict__ qp_W,
                  float* __restrict__ knv, float* __restrict__ vthr,
                  float* __restrict__ qbuf)
{
    __shared__ __align__(16) float h_s[32][64];    // 8 KB
    __shared__ __align__(16) float t1_s[32][128];  // 16 KB
    __shared__ __align__(16) float hn_s[32][64];   // 8 KB

    const int tid  = threadIdx.x;
    const int tok0 = blockIdx.x * 32;

    // ---- Stage A: embedding gather into LDS ----
#pragma unroll
    for (int k = 0; k < 8; ++k) {
        int e   = k * 256 + tid;
        int tok = e >> 6, i = e & 63;
        int s   = seq[tok0 + tok];
        h_s[tok][i] = embed_W[s * 64 + i];
    }
    __syncthreads();

    // ---- Stage B: FF1 (64 -> 128, ReLU) ----
    {
        const int j = tid & 127;
        const int g = tid >> 7;
        float w1c[64];
#pragma unroll
        for (int ii = 0; ii < 64; ++ii) w1c[ii] = ff_W1[ii * 128 + j];
        const float b1j = ff_b1[j];
#pragma unroll
        for (int tk = 0; tk < 16; ++tk) {
            const int tok = g * 16 + tk;
            const float4* h4 = (const float4*)h_s[tok];
            float a0 = b1j, a1 = 0.f, a2 = 0.f, a3 = 0.f;
#pragma unroll
            for (int w = 0; w < 16; ++w) {
                float4 hv = h4[w];
                a0 = fmaf(hv.x, w1c[4*w+0], a0);
                a1 = fmaf(hv.y, w1c[4*w+1], a1);
                a2 = fmaf(hv.z, w1c[4*w+2], a2);
                a3 = fmaf(hv.w, w1c[4*w+3], a3);
            }
            t1_s[tok][j] = fmaxf((a0 + a1) + (a2 + a3), 0.f);
        }
    }
    __syncthreads();

    // ---- Stage C: FF2 (128 -> 64) + residual + LayerNorm ----
    {
        const int i  = tid & 63;
        const int w4 = tid >> 6;
        const float b2i = ff_b2[i];
        const float gi  = ln_g[i];
        const float bi  = ln_b[i];
        float accf[8];
#pragma unroll
        for (int tk = 0; tk < 8; ++tk) accf[tk] = b2i;
#pragma unroll
        for (int h = 0; h < 2; ++h) {
            float w2c[64];
#pragma unroll
            for (int jj = 0; jj < 64; ++jj) w2c[jj] = ff_W2[(h*64 + jj) * 64 + i];
#pragma unroll
            for (int tk = 0; tk < 8; ++tk) {
                const int tok = w4 * 8 + tk;
                const float4* t4 = (const float4*)&t1_s[tok][h*64];
                float a0 = 0.f, a1 = 0.f, a2 = 0.f, a3 = 0.f;
#pragma unroll
                for (int w = 0; w < 16; ++w) {
                    float4 tv = t4[w];
                    a0 = fmaf(tv.x, w2c[4*w+0], a0);
                    a1 = fmaf(tv.y, w2c[4*w+1], a1);
                    a2 = fmaf(tv.z, w2c[4*w+2], a2);
                    a3 = fmaf(tv.w, w2c[4*w+3], a3);
                }
                accf[tk] += (a0 + a1) + (a2 + a3);
            }
        }
#pragma unroll
        for (int tk = 0; tk < 8; ++tk) {
            const int tok = w4 * 8 + tk;
            float x = h_s[tok][i] + accf[tk];
            float s = x;
#pragma unroll
            for (int m = 32; m > 0; m >>= 1) s += __shfl_xor(s, m);
            float mu = s * (1.f / 64.f);
            float d  = x - mu;
            float s2 = d * d;
#pragma unroll
            for (int m = 32; m > 0; m >>= 1) s2 += __shfl_xor(s2, m);
            float var = s2 * (1.f / 64.f);
            hn_s[tok][i] = d / sqrtf(var + 1e-5f) * gi + bi;
        }
    }
    __syncthreads();

    // ---- Stage D: kn/v into packed stream (t<1023) OR q (t==1023) ----
    {
        const int i  = tid & 63;
        const int w4 = tid >> 6;
        float kc[64], vc[64];
#pragma unroll
        for (int ii = 0; ii < 64; ++ii) {
            kc[ii] = kp_W[ii * 64 + i];
            vc[ii] = vp_W[ii * 64 + i];
        }
#pragma unroll
        for (int tk = 0; tk < 8; ++tk) {
            const int tok = w4 * 8 + tk;
            const int tg  = tok0 + tok;
            const int b   = tg >> 10;
            const int t   = tg & 1023;
            const float4* hn4 = (const float4*)hn_s[tok];
            if (t < 1023) {
                float ka0=0.f,ka1=0.f,ka2=0.f,ka3=0.f;
                float va0=0.f,va1=0.f,va2=0.f,va3=0.f;
#pragma unroll
                for (int w = 0; w < 16; ++w) {
                    float4 hv = hn4[w];
                    ka0 = fmaf(hv.x, kc[4*w+0], ka0);
                    ka1 = fmaf(hv.y, kc[4*w+1], ka1);
                    ka2 = fmaf(hv.z, kc[4*w+2], ka2);
                    ka3 = fmaf(hv.w, kc[4*w+3], ka3);
                    va0 = fmaf(hv.x, vc[4*w+0], va0);
                    va1 = fmaf(hv.y, vc[4*w+1], va1);
                    va2 = fmaf(hv.z, vc[4*w+2], va2);
                    va3 = fmaf(hv.w, vc[4*w+3], va3);
                }
                float ka = (ka0 + ka1) + (ka2 + ka3);
                float va = (va0 + va1) + (va2 + va3);
                float kn2 = ka * ka, vn2 = va * va;
#pragma unroll
                for (int m = 32; m > 0; m >>= 1) {
                    kn2 += __shfl_xor(kn2, m);
                    vn2 += __shfl_xor(vn2, m);
                }
                float knorm = fmaxf(sqrtf(kn2), 1e-12f);
                size_t row = ((size_t)b * 1024 + t) * 128;
                knv[row + i]      = ka / knorm;
                knv[row + 64 + i] = va;
                if (i == 0) vthr[b * 1024 + t] = 0.16f * vn2;   // SQUARED threshold
            } else {
                float qa0=0.f,qa1=0.f,qa2=0.f,qa3=0.f;
#pragma unroll
                for (int w = 0; w < 16; ++w) {
                    float4 hv = hn4[w];
                    qa0 = fmaf(hv.x, qp_W[(4*w+0)*64 + i], qa0);
                    qa1 = fmaf(hv.y, qp_W[(4*w+1)*64 + i], qa1);
                    qa2 = fmaf(hv.z, qp_W[(4*w+2)*64 + i], qa2);
                    qa3 = fmaf(hv.w, qp_W[(4*w+3)*64 + i], qa3);
                }
                qbuf[b * 64 + i] = (qa0 + qa1) + (qa2 + qa3);
            }
        }
    }
}

// ---------------------------------------------------------------------------
// Kernel 2: sequential fast-weight scan + output head.
// LAG-2 SOFTWARE PIPELINE, G=2 chunks, 2-wave column split.
//
// Body(u) (chunk u = steps 2u,2u+1), between barrier(u-1) and barrier(u):
//   1. exch-read rb(u-1) partials          [latency hidden under 2-5]
//   2. UPD with gd_{2u-4}, gd_{2u-3} (chunk u-2 gates, known)  -> M = M_{2u-3}
//   3. reload U,V <- rows 2u-2, 2u-1 (next body's UPD rows, LDS-resident)
//   4. DOT rows 2u, 2u+1 (sets S,T) with M_{2u-3}; publish partials
//   5. load S,T <- rows 2u+2, 2u+3 (next body's DOT rows)
//   6. chain for chunk u-1 (steps a=2u-2, b=2u-1):
//        vp_a = rb_a + c(2u-4,a) gd_{2u-4} + c(2u-3,a) gd_{2u-3}   (exact)
//        d_a0 = vv_a - vp_a; same for b (pre within-pair)
//        8-way DPP batch: S2,S1,S0 (d-products) + 5 kn-grams for next chain
//        gates: g_a = S2>th_a; e_b = S0 - g_a(2 c_ab S1 - c_ab^2 S2); g_b
//        gd_a, gd_b  -> consumed by UPD in body(u+1)
//   7. lgkmcnt(0); s_barrier
// All heavy streams (UPD/DOT/loads) are independent of the current chain ->
// LDS/exchange/DPP latencies are buried under FMA issue; the body is
// issue-bound. Fixed-role sets S,T,U,V (no rotation). 4-slot LDS ring (32KB)
// because bodies read one chunk BACKWARD (UPD-row reload).
// ---------------------------------------------------------------------------

template<int CTRL>
__device__ __forceinline__ float dppadd(float x) {
    int y = __builtin_amdgcn_update_dpp(0, __float_as_int(x), CTRL, 0xF, 0xF, true);
    return x + __int_as_float(y);
}

__device__ __forceinline__ float bcast63(float x) {
    return __int_as_float(__builtin_amdgcn_readlane(__float_as_int(x), 63));
}

__device__ __forceinline__ float wave_sum64(float x) {
    x = dppadd<0x111>(x); x = dppadd<0x112>(x);
    x = dppadd<0x114>(x); x = dppadd<0x118>(x);
    x = dppadd<0x142>(x); x = dppadd<0x143>(x);
    return bcast63(x);
}

// eight independent wave sums, DPP levels interleaved (issue-bound)
__device__ __forceinline__ void wsum8(float& a, float& b, float& c, float& d,
                                      float& e, float& f, float& g, float& h) {
#define LVL(C) a=dppadd<C>(a); b=dppadd<C>(b); c=dppadd<C>(c); d=dppadd<C>(d); \
               e=dppadd<C>(e); f=dppadd<C>(f); g=dppadd<C>(g); h=dppadd<C>(h);
    LVL(0x111) LVL(0x112) LVL(0x114) LVL(0x118) LVL(0x142) LVL(0x143)
#undef LVL
    a=bcast63(a); b=bcast63(b); c=bcast63(c); d=bcast63(d);
    e=bcast63(e); f=bcast63(f); g=bcast63(g); h=bcast63(h);
}

// load this wave's half of a kn row into half-set P (8 x ds_read_b128)
#define LOADK8(P, ROW) do { \
    const float* rA_ = (ROW) + (wid << 3); \
    const float* rB_ = rA_ + 4; \
    P##A0 = *(const v4f*)(rA_ +  0); P##A1 = *(const v4f*)(rA_ + 16); \
    P##A2 = *(const v4f*)(rA_ + 32); P##A3 = *(const v4f*)(rA_ + 48); \
    P##B0 = *(const v4f*)(rB_ +  0); P##B1 = *(const v4f*)(rB_ + 16); \
    P##B2 = *(const v4f*)(rB_ + 32); P##B3 = *(const v4f*)(rB_ + 48); \
} while (0)

// M(half) += G * P(half)   (branchless; G==0 exact no-op on finite P)
#define UPD8(P, G) do { \
    v4f gv_ = {G, G, G, G}; \
    mA0 = F4(gv_, P##A0, mA0); mA1 = F4(gv_, P##A1, mA1); \
    mA2 = F4(gv_, P##A2, mA2); mA3 = F4(gv_, P##A3, mA3); \
    mB0 = F4(gv_, P##B0, mB0); mB1 = F4(gv_, P##B1, mB1); \
    mB2 = F4(gv_, P##B2, mB2); mB3 = F4(gv_, P##B3, mB3); \
} while (0)

// Lag-2 pipelined body for chunk u.
//  U0R/U1R: rows 2u-2, 2u-1 (reload);  X0R/X1R: rows 2u+2, 2u+3 (next DOT);
//  PK0/PK1: rows 2u, 2u+1 (peeks);    T0P/T1P: &th2[2u], &th2[2u+1];
//  PAR = u&1 (exch slot parity).
#define BODY(U0R, U1R, X0R, X1R, PK0, PK1, T0P, T1P, PAR) do { \
    float2 oth_ = ((const float2*)pex[PAR][1 - wid])[lane]; \
    UPD8(U, gdp); \
    UPD8(V, gdq); \
    LOADK8(U, U0R); \
    LOADK8(V, U1R); \
    float knl2_ = (PK0)[lane]; \
    float knl3_ = (PK1)[lane]; \
    float vv2_  = (PK0)[64 + lane]; \
    float vv3_  = (PK1)[64 + lane]; \
    float th2_  = *(T0P); \
    float th3_  = *(T1P); \
    v4f qa_ = F4(mA0, SA0, F4(mA1, SA1, F4(mA2, SA2, mA3 * SA3))); \
    v4f qb_ = F4(mB0, SB0, F4(mB1, SB1, F4(mB2, SB2, mB3 * SB3))); \
    v4f q0_ = qa_ + qb_; \
    float own0n_ = (q0_.x + q0_.y) + (q0_.z + q0_.w); \
    v4f ra_ = F4(mA0, TA0, F4(mA1, TA1, F4(mA2, TA2, mA3 * TA3))); \
    v4f rb_ = F4(mB0, TB0, F4(mB1, TB1, F4(mB2, TB2, mB3 * TB3))); \
    v4f r0_ = ra_ + rb_; \
    float own1n_ = (r0_.x + r0_.y) + (r0_.z + r0_.w); \
    ((float2*)pex[(PAR) ^ 1][wid])[lane] = make_float2(own0n_, own1n_); \
    LOADK8(S, X0R); \
    LOADK8(T, X1R); \
    float base_a_ = pown0 + oth_.x; \
    float base_b_ = pown1 + oth_.y; \
    float vp_a_ = fmaf(cg0, gdp, fmaf(cg1, gdq, base_a_)); \
    float vp_b_ = fmaf(cg2, gdp, fmaf(cg3, gdq, base_b_)); \
    float da_ = vv_a - vp_a_; \
    float db_ = vv_b - vp_b_; \
    float x0_ = da_ * da_, x1_ = da_ * db_, x2_ = db_ * db_; \
    float y0_ = knl0 * knl2_, y1_ = knl1 * knl2_; \
    float y2_ = knl0 * knl3_, y3_ = knl1 * knl3_, y4_ = knl2_ * knl3_; \
    wsum8(x0_, x1_, x2_, y0_, y1_, y2_, y3_, y4_); \
    bool ga_ = x0_ > th_a; \
    float corr_ = fmaf(2.f * cab, x1_, -(cab * cab) * x0_); \
    float eb_ = ga_ ? (x2_ - corr_) : x2_; \
    bool gb_ = eb_ > th_b; \
    float gda_ = ga_ ? da_ : 0.f; \
    float gdb_ = gb_ ? fmaf(-cab, gda_, db_) : 0.f; \
    gdp = gda_; gdq = gdb_; \
    cg0 = y0_; cg1 = y1_; cg2 = y2_; cg3 = y3_; cab = y4_; \
    knl0 = knl2_; knl1 = knl3_; \
    vv_a = vv2_; vv_b = vv3_; th_a = th2_; th_b = th3_; \
    pown0 = own0n_; pown1 = own1n_; \
    asm volatile("s_waitcnt lgkmcnt(0)\n\ts_barrier" ::: "memory"); \
} while (0)

// 8 bodies covering one 16-row buffer (chunks 8c..8c+7).
#define BUF8_L(PB, CB, NB, TP) \
    BODY((PB)+14*128,(PB)+15*128,(CB)+2*128,(CB)+3*128,(CB)+0*128,(CB)+1*128,(TP)+0,(TP)+1,0); \
    BODY((CB)+0*128,(CB)+1*128,(CB)+4*128,(CB)+5*128,(CB)+2*128,(CB)+3*128,(TP)+2,(TP)+3,1); \
    BODY((CB)+2*128,(CB)+3*128,(CB)+6*128,(CB)+7*128,(CB)+4*128,(CB)+5*128,(TP)+4,(TP)+5,0); \
    BODY((CB)+4*128,(CB)+5*128,(CB)+8*128,(CB)+9*128,(CB)+6*128,(CB)+7*128,(TP)+6,(TP)+7,1); \
    BODY((CB)+6*128,(CB)+7*128,(CB)+10*128,(CB)+11*128,(CB)+8*128,(CB)+9*128,(TP)+8,(TP)+9,0); \
    BODY((CB)+8*128,(CB)+9*128,(CB)+12*128,(CB)+13*128,(CB)+10*128,(CB)+11*128,(TP)+10,(TP)+11,1); \
    BODY((CB)+10*128,(CB)+11*128,(CB)+14*128,(CB)+15*128,(CB)+12*128,(CB)+13*128,(TP)+12,(TP)+13,0); \
    BODY((CB)+12*128,(CB)+13*128,(NB)+0*128,(NB)+1*128,(CB)+14*128,(CB)+15*128,(TP)+14,(TP)+15,1);

// async copy: 1024 B contiguous global -> contiguous LDS (one inst)
__device__ __forceinline__ void gl2lds_1k(const float* g, float* l, int lane) {
    __builtin_amdgcn_global_load_lds(
        (const __attribute__((address_space(1))) void*)(g + lane * 4),
        (__attribute__((address_space(3))) void*)l, 16, 0, 0);
}

// wave w stages rows 8w..8w+7 of a 16-row buffer (4 KB = 4 insts)
__device__ __forceinline__ void prefetch_half(const float* g, float* l,
                                              int lane, int wid) {
#pragma unroll
    for (int j = 0; j < 4; ++j)
        gl2lds_1k(g + wid * 1024 + j * 256, l + wid * 1024 + j * 256, lane);
}

__global__ __launch_bounds__(128, 1)
void scan_kernel(const float* __restrict__ knv,
                 const float* __restrict__ vthr,
                 const float* __restrict__ qbuf,
                 const float* __restrict__ rp_W, const float* __restrict__ rp_b,
                 const float* __restrict__ out_W, const float* __restrict__ out_b,
                 float* __restrict__ out)
{
    const int b    = blockIdx.x;
    const int tid  = threadIdx.x;
    const int lane = tid & 63;
    const int wid  = tid >> 6;
    const float* knvb = knv  + (size_t)b * 1024 * 128;
    const float* thrb = vthr + (size_t)b * 1024;

    __shared__ __align__(16) float thr_s[1040];      // th^2 per step
    __shared__ __align__(16) float buf[4 * 2048];    // 4-slot ring, 32 KB
    __shared__ __align__(16) float pex[2][2][128];   // [parity][wave][lane*2]
    __shared__ float sh[64];

    // M half: chains cA=2*wid (v4f idx cA,cA+4,cA+8,cA+12), cB=cA+1
    v4f mA0={0,0,0,0},mA1={0,0,0,0},mA2={0,0,0,0},mA3={0,0,0,0};
    v4f mB0={0,0,0,0},mB1={0,0,0,0},mB2={0,0,0,0},mB3={0,0,0,0};
    // FIXED-role half-sets: S,T = DOT rows; U,V = UPD rows
    v4f SA0,SA1,SA2,SA3,SB0,SB1,SB2,SB3;
    v4f TA0,TA1,TA2,TA3,TB0,TB1,TB2,TB3;
    v4f UA0,UA1,UA2,UA3,UB0,UB1,UB2,UB3;
    v4f VA0,VA1,VA2,VA3,VB0,VB1,VB2,VB3;

    // staging: buffers 0,1,2 into slots 0,1,2; wave 0 also loads thr
    if (wid == 0) {
#pragma unroll
        for (int w = 0; w < 4; ++w) gl2lds_1k(thrb + w * 256, thr_s + w * 256, lane);
    }
    prefetch_half(knvb,        buf,        lane, wid);
    prefetch_half(knvb + 2048, buf + 2048, lane, wid);
    prefetch_half(knvb + 4096, buf + 4096, lane, wid);

    // zero pex (both parity slots): 512 floats / 128 threads = 4 each
    {
        float4 z4 = make_float4(0.f, 0.f, 0.f, 0.f);
        ((float4*)pex)[tid] = z4;
    }

    // thr + buffers 0,1 resident; buffer 2 (4 insts) in flight
    asm volatile("s_waitcnt vmcnt(4) lgkmcnt(0)\n\ts_barrier" ::: "memory");

    // prologue: body(0) DOTs rows 0,1; its UPD is a gd=0 no-op on finite data
    LOADK8(S, buf);            // kn_0
    LOADK8(T, buf + 128);      // kn_1
    LOADK8(U, buf);            // finite dummy
    LOADK8(V, buf);            // finite dummy
    float gdp = 0.f, gdq = 0.f;
    float cg0 = 0.f, cg1 = 0.f, cg2 = 0.f, cg3 = 0.f, cab = 0.f;
    float knl0 = 0.f, knl1 = 0.f;
    float vv_a = 0.f, vv_b = 0.f;
    float th_a = 1e30f, th_b = 1e30f;    // dummy chain (chunk -1) gates = 0
    float pown0 = 0.f, pown1 = 0.f;

#pragma unroll 1
    for (int c = 0; c < 62; ++c) {
        // own outstanding <= 8 (buffers c+1, c+2); vmcnt(4) -> buffer c+1
        // resident; per-body barriers give cross-wave visibility.
        asm volatile("s_waitcnt vmcnt(4)" ::: "memory");
        const float* cb = buf + (c & 3) * 2048;
        const float* nb = buf + ((c + 1) & 3) * 2048;
        const float* pb = (c == 0) ? cb : buf + ((c - 1) & 3) * 2048;
        const float* tp = thr_s + c * 16;
        BUF8_L(pb, cb, nb, tp)
        // slot (c+3)&3 == (c-1)&3 holds buffer c-1: dead after this iter's
        // first body -> safe to overwrite now (prefetch after all 8 bodies).
        if (c <= 60)
            prefetch_half(knvb + (size_t)(c + 3) * 2048,
                          buf + ((c + 3) & 3) * 2048, lane, wid);
    }
    asm volatile("s_waitcnt vmcnt(0)" ::: "memory");
    asm volatile("s_barrier" ::: "memory");   // buffers 62,63 fully staged
    {   // buffer 62: PB = slot 1 (buffer 61), CB = slot 2, NB = slot 3
        const float* pb = buf + 1 * 2048;
        const float* cb = buf + 2 * 2048;
        const float* nb = buf + 3 * 2048;
        const float* tp = thr_s + 62 * 16;
        BUF8_L(pb, cb, nb, tp)
    }
    {   // buffer 63: PB = slot 2, CB = slot 3, NB = dummy (slot 0, stale-finite)
        const float* pb = buf + 2 * 2048;
        const float* cb = buf + 3 * 2048;
        const float* nb = buf;
        const float* tp = thr_s + 63 * 16;
        BUF8_L(pb, cb, nb, tp)
    }

    // ---- epilogue (u = 512): finish chunks 510 and 511 ----
    {
        // exch of rb(511): body 511 (PAR=1) published to slot 0
        float2 oth_ = ((const float2*)pex[0][1 - wid])[lane];
        // apply gd_{1020}, gd_{1021} (chunk 510 gates; U,V = rows 1020,1021)
        UPD8(U, gdp);
        UPD8(V, gdq);                          // M = M_{1021}
        // gate for step 1022 (step 1023 is a dummy)
        float base_a_ = pown0 + oth_.x;
        float vp_a_ = fmaf(cg0, gdp, fmaf(cg1, gdq, base_a_));
        float da_ = vv_a - vp_a_;              // vv_a = v_1022 (peeked body 511)
        float e_ = wave_sum64(da_ * da_);
        float gda_ = (e_ > th_a) ? da_ : 0.f;
        // kn_1022 = buffer 63 (slot 3) row 14
        LOADK8(S, buf + 3 * 2048 + 14 * 128);
        UPD8(S, gda_);                         // M = M_{1022} final
    }

    // ---- output head: vq = M q (split + exchange), then wave 0 finishes ----
    {
        const v4f* qq = (const v4f*)(qbuf + b * 64);
        const int w2 = 2 * wid;
        v4f aqA = F4(mA0, qq[w2+0], F4(mA1, qq[w2+4],
                  F4(mA2, qq[w2+8],  mA3 * qq[w2+12])));
        v4f aqB = F4(mB0, qq[w2+1], F4(mB1, qq[w2+5],
                  F4(mB2, qq[w2+9],  mB3 * qq[w2+13])));
        v4f aq = aqA + aqB;
        float vq_own = (aq.x + aq.y) + (aq.z + aq.w);
        ((float*)pex)[wid * 64 + lane] = vq_own;
        asm volatile("s_waitcnt lgkmcnt(0)\n\ts_barrier" ::: "memory");
        float vq = vq_own + ((float*)pex)[(1 - wid) * 64 + lane];

        if (wid == 0) {
            sh[lane] = vq;
            asm volatile("s_waitcnt lgkmcnt(0)" ::: "memory");
            float r = rp_b[lane];
#pragma unroll
            for (int ii = 0; ii < 64; ++ii) r = fmaf(sh[ii], rp_W[ii * 64 + lane], r);
            asm volatile("s_waitcnt lgkmcnt(0)" ::: "memory");
            sh[lane] = r;
            asm volatile("s_waitcnt lgkmcnt(0)" ::: "memory");
            float o = out_b[lane];
#pragma unroll
            for (int ii = 0; ii < 64; ++ii) o = fmaf(sh[ii], out_W[ii * 64 + lane], o);
            out[b * 64 + lane] = o;
        }
    }
}

// ---------------------------------------------------------------------------
// Launch. Workspace (fp32): knv[64][1024][128] (33.55 MB, t=1023 row unused) |
// vthr[64][1024] (262 KB) | qbuf[64][64]. Total ~33.9 MB.
// ---------------------------------------------------------------------------
extern "C" void kernel_launch(void* const* d_in, const int* in_sizes, int n_in,
                              void* d_out, int out_size, void* d_ws, size_t ws_size,
                              hipStream_t stream)
{
    const int*   seq   = (const int*)  d_in[0];
    const float* embed = (const float*)d_in[1];
    const float* ffW1  = (const float*)d_in[2];
    const float* ffb1  = (const float*)d_in[3];
    const float* ffW2  = (const float*)d_in[4];
    const float* ffb2  = (const float*)d_in[5];
    const float* lng   = (const float*)d_in[6];
    const float* lnb   = (const float*)d_in[7];
    const float* kpW   = (const float*)d_in[8];
    const float* vpW   = (const float*)d_in[9];
    const float* qpW   = (const float*)d_in[10];
    const float* rpW   = (const float*)d_in[11];
    const float* rpb   = (const float*)d_in[12];
    const float* outW  = (const float*)d_in[13];
    const float* outb  = (const float*)d_in[14];
    float* out = (float*)d_out;

    float* knv  = (float*)d_ws;
    float* vthr = knv  + (size_t)64 * 1024 * 128;
    float* qbuf = vthr + (size_t)64 * 1024;

    token_kernel<<<2048, 256, 0, stream>>>(seq, embed, ffW1, ffb1, ffW2, ffb2,
                                           lng, lnb, kpW, vpW, qpW,
                                           knv, vthr, qbuf);
    scan_kernel<<<64, 128, 0, stream>>>(knv, vthr, qbuf,
                                        rpW, rpb, outW, outb, out);
}

// Round 8
// 367.141 us; speedup vs baseline: 1.1656x; 1.1656x over previous
//
#include <hip/hip_runtime.h>
#include <hip/hip_bf16.h>
#include <math.h>

// Problem constants (reference: B=64, L=1024, H=64, VOCAB=64)
#define BB 64
#define LL 1024
#define HH 64

typedef float v4f __attribute__((ext_vector_type(4)));
#define F4 __builtin_elementwise_fma

// ---------------------------------------------------------------------------
// Kernel 1: per-token phase (unchanged).
// ---------------------------------------------------------------------------
__global__ __launch_bounds__(256, 1)
void token_kernel(const int* __restrict__ seq,
                  const float* __restrict__ embed_W,
                  const float* __restrict__ ff_W1, const float* __restrict__ ff_b1,
                  const float* __restrict__ ff_W2, const float* __restrict__ ff_b2,
                  const float* __restrict__ ln_g, const float* __restrict__ ln_b,
                  const float* __restrict__ kp_W, const float* __restrict__ vp_W,
                  const float* __restrict__ qp_W,
                  float* __restrict__ knv, float* __restrict__ vthr,
                  float* __restrict__ qbuf)
{
    __shared__ __align__(16) float h_s[32][64];    // 8 KB
    __shared__ __align__(16) float t1_s[32][128];  // 16 KB
    __shared__ __align__(16) float hn_s[32][64];   // 8 KB

    const int tid  = threadIdx.x;
    const int tok0 = blockIdx.x * 32;

    // ---- Stage A: embedding gather into LDS ----
#pragma unroll
    for (int k = 0; k < 8; ++k) {
        int e   = k * 256 + tid;
        int tok = e >> 6, i = e & 63;
        int s   = seq[tok0 + tok];
        h_s[tok][i] = embed_W[s * 64 + i];
    }
    __syncthreads();

    // ---- Stage B: FF1 (64 -> 128, ReLU) ----
    {
        const int j = tid & 127;
        const int g = tid >> 7;
        float w1c[64];
#pragma unroll
        for (int ii = 0; ii < 64; ++ii) w1c[ii] = ff_W1[ii * 128 + j];
        const float b1j = ff_b1[j];
#pragma unroll
        for (int tk = 0; tk < 16; ++tk) {
            const int tok = g * 16 + tk;
            const float4* h4 = (const float4*)h_s[tok];
            float a0 = b1j, a1 = 0.f, a2 = 0.f, a3 = 0.f;
#pragma unroll
            for (int w = 0; w < 16; ++w) {
                float4 hv = h4[w];
                a0 = fmaf(hv.x, w1c[4*w+0], a0);
                a1 = fmaf(hv.y, w1c[4*w+1], a1);
                a2 = fmaf(hv.z, w1c[4*w+2], a2);
                a3 = fmaf(hv.w, w1c[4*w+3], a3);
            }
            t1_s[tok][j] = fmaxf((a0 + a1) + (a2 + a3), 0.f);
        }
    }
    __syncthreads();

    // ---- Stage C: FF2 (128 -> 64) + residual + LayerNorm ----
    {
        const int i  = tid & 63;
        const int w4 = tid >> 6;
        const float b2i = ff_b2[i];
        const float gi  = ln_g[i];
        const float bi  = ln_b[i];
        float accf[8];
#pragma unroll
        for (int tk = 0; tk < 8; ++tk) accf[tk] = b2i;
#pragma unroll
        for (int h = 0; h < 2; ++h) {
            float w2c[64];
#pragma unroll
            for (int jj = 0; jj < 64; ++jj) w2c[jj] = ff_W2[(h*64 + jj) * 64 + i];
#pragma unroll
            for (int tk = 0; tk < 8; ++tk) {
                const int tok = w4 * 8 + tk;
                const float4* t4 = (const float4*)&t1_s[tok][h*64];
                float a0 = 0.f, a1 = 0.f, a2 = 0.f, a3 = 0.f;
#pragma unroll
                for (int w = 0; w < 16; ++w) {
                    float4 tv = t4[w];
                    a0 = fmaf(tv.x, w2c[4*w+0], a0);
                    a1 = fmaf(tv.y, w2c[4*w+1], a1);
                    a2 = fmaf(tv.z, w2c[4*w+2], a2);
                    a3 = fmaf(tv.w, w2c[4*w+3], a3);
                }
                accf[tk] += (a0 + a1) + (a2 + a3);
            }
        }
#pragma unroll
        for (int tk = 0; tk < 8; ++tk) {
            const int tok = w4 * 8 + tk;
            float x = h_s[tok][i] + accf[tk];
            float s = x;
#pragma unroll
            for (int m = 32; m > 0; m >>= 1) s += __shfl_xor(s, m);
            float mu = s * (1.f / 64.f);
            float d  = x - mu;
            float s2 = d * d;
#pragma unroll
            for (int m = 32; m > 0; m >>= 1) s2 += __shfl_xor(s2, m);
            float var = s2 * (1.f / 64.f);
            hn_s[tok][i] = d / sqrtf(var + 1e-5f) * gi + bi;
        }
    }
    __syncthreads();

    // ---- Stage D: kn/v into packed stream (t<1023) OR q (t==1023) ----
    {
        const int i  = tid & 63;
        const int w4 = tid >> 6;
        float kc[64], vc[64];
#pragma unroll
        for (int ii = 0; ii < 64; ++ii) {
            kc[ii] = kp_W[ii * 64 + i];
            vc[ii] = vp_W[ii * 64 + i];
        }
#pragma unroll
        for (int tk = 0; tk < 8; ++tk) {
            const int tok = w4 * 8 + tk;
            const int tg  = tok0 + tok;
            const int b   = tg >> 10;
            const int t   = tg & 1023;
            const float4* hn4 = (const float4*)hn_s[tok];
            if (t < 1023) {
                float ka0=0.f,ka1=0.f,ka2=0.f,ka3=0.f;
                float va0=0.f,va1=0.f,va2=0.f,va3=0.f;
#pragma unroll
                for (int w = 0; w < 16; ++w) {
                    float4 hv = hn4[w];
                    ka0 = fmaf(hv.x, kc[4*w+0], ka0);
                    ka1 = fmaf(hv.y, kc[4*w+1], ka1);
                    ka2 = fmaf(hv.z, kc[4*w+2], ka2);
                    ka3 = fmaf(hv.w, kc[4*w+3], ka3);
                    va0 = fmaf(hv.x, vc[4*w+0], va0);
                    va1 = fmaf(hv.y, vc[4*w+1], va1);
                    va2 = fmaf(hv.z, vc[4*w+2], va2);
                    va3 = fmaf(hv.w, vc[4*w+3], va3);
                }
                float ka = (ka0 + ka1) + (ka2 + ka3);
                float va = (va0 + va1) + (va2 + va3);
                float kn2 = ka * ka, vn2 = va * va;
#pragma unroll
                for (int m = 32; m > 0; m >>= 1) {
                    kn2 += __shfl_xor(kn2, m);
                    vn2 += __shfl_xor(vn2, m);
                }
                float knorm = fmaxf(sqrtf(kn2), 1e-12f);
                size_t row = ((size_t)b * 1024 + t) * 128;
                knv[row + i]      = ka / knorm;
                knv[row + 64 + i] = va;
                if (i == 0) vthr[b * 1024 + t] = 0.16f * vn2;   // SQUARED threshold
            } else {
                float qa0=0.f,qa1=0.f,qa2=0.f,qa3=0.f;
#pragma unroll
                for (int w = 0; w < 16; ++w) {
                    float4 hv = hn4[w];
                    qa0 = fmaf(hv.x, qp_W[(4*w+0)*64 + i], qa0);
                    qa1 = fmaf(hv.y, qp_W[(4*w+1)*64 + i], qa1);
                    qa2 = fmaf(hv.z, qp_W[(4*w+2)*64 + i], qa2);
                    qa3 = fmaf(hv.w, qp_W[(4*w+3)*64 + i], qa3);
                }
                qbuf[b * 64 + i] = (qa0 + qa1) + (qa2 + qa3);
            }
        }
    }
}

// ---------------------------------------------------------------------------
// Kernel 2: sequential fast-weight scan + output head.
// ROUND-6 G=2 CHUNK STRUCTURE, 4-WAVE COLUMN SPLIT (block = 256 threads).
//
// Wave w owns columns [16w, 16w+16) (v4f indices 4w..4w+3). Per chunk each
// wave does quarter-DOTs (4 FMA each) and quarter-UPDs (4 FMA each); the
// reduce batch + gate algebra run redundantly in all 4 waves. CRITICAL
// determinism rule: all waves compute the gate inputs BIT-IDENTICALLY —
// every wave reads ALL FOUR pex slots and sums in the fixed tree
// (p0+p1)+(p2+p3); d/vv/th/gram values are identical per lane by
// construction. Divergent gates would silently fork M across waves.
//
// Chunk u (steps 2u, 2u+1), same math as round 6:
//   UPD(gd_{2u-2}), UPD(gd_{2u-1}) -> M = M_{2u-1}; quarter-DOT rows 2u,2u+1;
//   publish float2; lgkmcnt(0)+barrier; read 4 partials; d00,d01;
//   wsum4{|d00|^2, d00.d01, |d01|^2, gram_next}; gates via exact e1
//   expansion: e1 = S0 - g0(2 c3 S1 - c3^2 S2); gd's for next chunk's UPDs.
//
// grid = 64 (one block/batch), block = 256 (4 waves). Lane i owns M row i;
// staging: wave w stages rows 4w..4w+3 of each 16-row buffer (2 insts),
// counted vmcnt(2); 3-slot ring as before.
// ---------------------------------------------------------------------------

template<int CTRL>
__device__ __forceinline__ float dppadd(float x) {
    int y = __builtin_amdgcn_update_dpp(0, __float_as_int(x), CTRL, 0xF, 0xF, true);
    return x + __int_as_float(y);
}

__device__ __forceinline__ float bcast63(float x) {
    return __int_as_float(__builtin_amdgcn_readlane(__float_as_int(x), 63));
}

// full-wave (64 lane) sum, result broadcast (prologue use)
__device__ __forceinline__ float wave_sum64(float x) {
    x = dppadd<0x111>(x); x = dppadd<0x112>(x);
    x = dppadd<0x114>(x); x = dppadd<0x118>(x);
    x = dppadd<0x142>(x); x = dppadd<0x143>(x);
    return bcast63(x);
}

// four independent wave sums, DPP levels interleaved (latency amortized)
__device__ __forceinline__ void wsum4(float& a, float& b, float& c, float& d) {
    a = dppadd<0x111>(a); b = dppadd<0x111>(b); c = dppadd<0x111>(c); d = dppadd<0x111>(d);
    a = dppadd<0x112>(a); b = dppadd<0x112>(b); c = dppadd<0x112>(c); d = dppadd<0x112>(d);
    a = dppadd<0x114>(a); b = dppadd<0x114>(b); c = dppadd<0x114>(c); d = dppadd<0x114>(d);
    a = dppadd<0x118>(a); b = dppadd<0x118>(b); c = dppadd<0x118>(c); d = dppadd<0x118>(d);
    a = dppadd<0x142>(a); b = dppadd<0x142>(b); c = dppadd<0x142>(c); d = dppadd<0x142>(d);
    a = dppadd<0x143>(a); b = dppadd<0x143>(b); c = dppadd<0x143>(c); d = dppadd<0x143>(d);
    a = bcast63(a); b = bcast63(b); c = bcast63(c); d = bcast63(d);
}

// load this wave's quarter of a kn row into quarter-set P (4 x ds_read_b128)
#define LOADK4(P, ROW) do { \
    const float* r_ = (ROW) + (wid << 4); \
    P##0 = *(const v4f*)(r_ + 0);  P##1 = *(const v4f*)(r_ + 4); \
    P##2 = *(const v4f*)(r_ + 8);  P##3 = *(const v4f*)(r_ + 12); \
} while (0)

// M(quarter) += G * P(quarter)   (branchless; G==0 exact no-op on finite P)
#define UPD4(P, G) do { \
    v4f gv_ = {G, G, G, G}; \
    m0 = F4(gv_, P##0, m0); m1 = F4(gv_, P##1, m1); \
    m2 = F4(gv_, P##2, m2); m3 = F4(gv_, P##3, m3); \
} while (0)

// One chunk u (steps 2u, 2u+1).  UP,UQ = UPD sources (then refilled from
// ROW2/ROW3 = rows 2u+2, 2u+3); XR,XS = DOT sources (kn_{2u}, kn_{2u+1}).
// Carried scalars: gdp=gd_{2u-2}, gdq=gd_{2u-1} (per-lane, identical across
// waves), vv0/vv1 = v_{2u}/v_{2u+1}[lane], th0/th1, c3 = kn_{2u}.kn_{2u+1}.
#define CHUNK2(UP, UQ, XR, XS, ROW2, ROW3, TH2P, TH3P, PAR) do { \
    UPD4(UP, gdp); \
    UPD4(UQ, gdq); \
    v4f q_ = F4(m0, XR##0, F4(m1, XR##1, F4(m2, XR##2, m3 * XR##3))); \
    float own0_ = (q_.x + q_.y) + (q_.z + q_.w); \
    v4f r_ = F4(m0, XS##0, F4(m1, XS##1, F4(m2, XS##2, m3 * XS##3))); \
    float own1_ = (r_.x + r_.y) + (r_.z + r_.w); \
    ((float2*)pex[PAR][wid])[lane] = make_float2(own0_, own1_); \
    asm volatile("s_waitcnt lgkmcnt(0)\n\ts_barrier" ::: "memory"); \
    float2 p0_ = ((const float2*)pex[PAR][0])[lane]; \
    float2 p1_ = ((const float2*)pex[PAR][1])[lane]; \
    float2 p2_ = ((const float2*)pex[PAR][2])[lane]; \
    float2 p3_ = ((const float2*)pex[PAR][3])[lane]; \
    float knl2_ = (ROW2)[lane]; \
    float knl3_ = (ROW3)[lane]; \
    float vv2_  = (ROW2)[64 + lane]; \
    float vv3_  = (ROW3)[64 + lane]; \
    float th2_  = *(TH2P); \
    float th3_  = *(TH3P); \
    LOADK4(UP, ROW2); \
    LOADK4(UQ, ROW3); \
    float base0_ = (p0_.x + p1_.x) + (p2_.x + p3_.x); \
    float base1_ = (p0_.y + p1_.y) + (p2_.y + p3_.y); \
    float d00_ = vv0 - base0_; \
    float d01_ = vv1 - base1_; \
    float x0_ = d00_ * d00_, x1_ = d00_ * d01_; \
    float x2_ = d01_ * d01_, x3_ = knl2_ * knl3_; \
    wsum4(x0_, x1_, x2_, x3_); \
    bool g0_ = x0_ > th0; \
    float corr_ = fmaf(2.f * c3, x1_, -(c3 * c3) * x0_); \
    float e1_ = g0_ ? (x2_ - corr_) : x2_; \
    bool g1_ = e1_ > th1; \
    float gd0_ = g0_ ? d00_ : 0.f; \
    float d1_  = fmaf(-c3, gd0_, d01_); \
    gdp = gd0_; \
    gdq = g1_ ? d1_ : 0.f; \
    vv0 = vv2_; vv1 = vv3_; th0 = th2_; th1 = th3_; c3 = x3_; \
} while (0)

// 8 chunks covering one 16-row buffer (steps 16c .. 16c+15).
#define BUF8(CB, NB, TP) \
    CHUNK2(U,V,S,T,(CB)+2*128, (CB)+3*128, (TP)+2, (TP)+3, 0); \
    CHUNK2(S,T,U,V,(CB)+4*128, (CB)+5*128, (TP)+4, (TP)+5, 1); \
    CHUNK2(U,V,S,T,(CB)+6*128, (CB)+7*128, (TP)+6, (TP)+7, 0); \
    CHUNK2(S,T,U,V,(CB)+8*128, (CB)+9*128, (TP)+8, (TP)+9, 1); \
    CHUNK2(U,V,S,T,(CB)+10*128,(CB)+11*128,(TP)+10,(TP)+11,0); \
    CHUNK2(S,T,U,V,(CB)+12*128,(CB)+13*128,(TP)+12,(TP)+13,1); \
    CHUNK2(U,V,S,T,(CB)+14*128,(CB)+15*128,(TP)+14,(TP)+15,0); \
    CHUNK2(S,T,U,V,(NB)+0*128, (NB)+1*128, (TP)+16,(TP)+17,1);

// async copy: 1024 B contiguous global -> contiguous LDS (one inst)
__device__ __forceinline__ void gl2lds_1k(const float* g, float* l, int lane) {
    __builtin_amdgcn_global_load_lds(
        (const __attribute__((address_space(1))) void*)(g + lane * 4),
        (__attribute__((address_space(3))) void*)l, 16, 0, 0);
}

// wave w stages rows 4w..4w+3 of a 16-row buffer (2 KB = 2 insts)
__device__ __forceinline__ void prefetch_quarter(const float* g, float* l,
                                                 int lane, int wid) {
#pragma unroll
    for (int j = 0; j < 2; ++j)
        gl2lds_1k(g + wid * 512 + j * 256, l + wid * 512 + j * 256, lane);
}

__global__ __launch_bounds__(256, 1)
void scan_kernel(const float* __restrict__ knv,
                 const float* __restrict__ vthr,
                 const float* __restrict__ qbuf,
                 const float* __restrict__ rp_W, const float* __restrict__ rp_b,
                 const float* __restrict__ out_W, const float* __restrict__ out_b,
                 float* __restrict__ out)
{
    const int b    = blockIdx.x;
    const int tid  = threadIdx.x;
    const int lane = tid & 63;
    const int wid  = tid >> 6;
    const float* knvb = knv  + (size_t)b * 1024 * 128;
    const float* thrb = vthr + (size_t)b * 1024;

    __shared__ __align__(16) float thr_s[1040];      // th^2 per step
    __shared__ __align__(16) float buf[3 * 2048];    // 3 x 8 KB buffers
    __shared__ __align__(16) float pex[2][4][128];   // [parity][wave][lane*2]
    __shared__ float sh[64];

    // M quarter: columns [16*wid, 16*wid+16) of lane's row (4 v4f)
    v4f m0={0,0,0,0}, m1={0,0,0,0}, m2={0,0,0,0}, m3={0,0,0,0};
    // four kn quarter-sets; roles alternate per chunk parity
    v4f S0,S1,S2,S3;
    v4f T0,T1,T2,T3;
    v4f U0,U1,U2,U3;
    v4f V0,V1,V2,V3;

    // staging: wave 0 also loads thr (4 insts); each wave 2 insts/buffer
    if (wid == 0) {
#pragma unroll
        for (int w = 0; w < 4; ++w) gl2lds_1k(thrb + w * 256, thr_s + w * 256, lane);
    }
    prefetch_quarter(knvb,        buf,        lane, wid);
    prefetch_quarter(knvb + 2048, buf + 2048, lane, wid);
    prefetch_quarter(knvb + 4096, buf + 4096, lane, wid);

    // zero pex: 1024 floats / 256 threads = 1 float4 each
    {
        float4 z4 = make_float4(0.f, 0.f, 0.f, 0.f);
        ((float4*)pex)[tid] = z4;
    }

    // thr + buffers 0,1 resident own-wave (buffer 2 = 2 insts in flight);
    // barrier makes all waves' quarters visible.
    asm volatile("s_waitcnt vmcnt(2) lgkmcnt(0)\n\ts_barrier" ::: "memory");

    // prologue: chunk 0 expects S=kn_0, T=kn_1, U=V = kn_{-2,-1} = 0
    LOADK4(S, buf);
    LOADK4(T, buf + 128);
    {
        v4f z_ = {0.f, 0.f, 0.f, 0.f};
        U0=z_;U1=z_;U2=z_;U3=z_;
        V0=z_;V1=z_;V2=z_;V3=z_;
    }
    float vv0 = buf[64 + lane];          // v_0[lane]
    float vv1 = buf[192 + lane];         // v_1[lane]
    float th0 = thr_s[0];
    float th1 = thr_s[1];
    float c3  = wave_sum64(buf[lane] * buf[128 + lane]);   // kn_0 . kn_1
    float gdp = 0.f, gdq = 0.f;

#pragma unroll 1
    for (int c = 0; c < 62; ++c) {
        // own outstanding <= 4 (buffers c+1, c+2); vmcnt(2) -> buffer c+1
        // resident own-wave; chunk barriers give cross-wave visibility.
        asm volatile("s_waitcnt vmcnt(2)" ::: "memory");
        const float* cb = buf + (c % 3) * 2048;
        const float* nb = buf + ((c + 1) % 3) * 2048;
        const float* tp = thr_s + c * 16;
        BUF8(cb, nb, tp)
        if (c <= 60)
            prefetch_quarter(knvb + (size_t)(c + 3) * 2048,
                             buf + (c % 3) * 2048, lane, wid);
    }
    asm volatile("s_waitcnt vmcnt(0)" ::: "memory");
    asm volatile("s_barrier" ::: "memory");   // all waves' buffers 62,63 staged
    {   // buffer 62 (slot 2), lookahead into buffer 63 (slot 0)
        const float* cb = buf + 2 * 2048;
        const float* nb = buf;
        const float* tp = thr_s + 62 * 16;
        BUF8(cb, nb, tp)
    }
    {   // buffer 63 (slot 0): steps 1008..1023 (1023 = dummy); NB dummy slot 1
        const float* cb = buf;
        const float* nb = buf + 2048;
        const float* tp = thr_s + 63 * 16;
        BUF8(cb, nb, tp)
    }
    // final update: M_{1022} = M_{1021} + gd_{1022} kn_{1022}^T
    // (gdp = gd_{1022}; U holds kn_{1022}: DOT source of the last chunk)
    UPD4(U, gdp);

    // ---- output head: vq = M q (quarter + exchange), wave 0 finishes ----
    {
        const v4f* qq = (const v4f*)(qbuf + b * 64);
        const int w4i = 4 * wid;
        v4f aq = F4(m0, qq[w4i+0], F4(m1, qq[w4i+1],
                 F4(m2, qq[w4i+2],  m3 * qq[w4i+3])));
        float vq_own = (aq.x + aq.y) + (aq.z + aq.w);
        pex[0][wid][lane] = vq_own;
        asm volatile("s_waitcnt lgkmcnt(0)\n\ts_barrier" ::: "memory");

        if (wid == 0) {
            float vq = (pex[0][0][lane] + pex[0][1][lane])
                     + (pex[0][2][lane] + pex[0][3][lane]);
            sh[lane] = vq;
            asm volatile("s_waitcnt lgkmcnt(0)" ::: "memory");
            float r = rp_b[lane];
#pragma unroll
            for (int ii = 0; ii < 64; ++ii) r = fmaf(sh[ii], rp_W[ii * 64 + lane], r);
            asm volatile("s_waitcnt lgkmcnt(0)" ::: "memory");
            sh[lane] = r;
            asm volatile("s_waitcnt lgkmcnt(0)" ::: "memory");
            float o = out_b[lane];
#pragma unroll
            for (int ii = 0; ii < 64; ++ii) o = fmaf(sh[ii], out_W[ii * 64 + lane], o);
            out[b * 64 + lane] = o;
        }
    }
}

// ---------------------------------------------------------------------------
// Launch. Workspace (fp32): knv[64][1024][128] (33.55 MB, t=1023 row unused) |
// vthr[64][1024] (262 KB) | qbuf[64][64]. Total ~33.9 MB.
// ---------------------------------------------------------------------------
extern "C" void kernel_launch(void* const* d_in, const int* in_sizes, int n_in,
                              void* d_out, int out_size, void* d_ws, size_t ws_size,
                              hipStream_t stream)
{
    const int*   seq   = (const int*)  d_in[0];
    const float* embed = (const float*)d_in[1];
    const float* ffW1  = (const float*)d_in[2];
    const float* ffb1  = (const float*)d_in[3];
    const float* ffW2  = (const float*)d_in[4];
    const float* ffb2  = (const float*)d_in[5];
    const float* lng   = (const float*)d_in[6];
    const float* lnb   = (const float*)d_in[7];
    const float* kpW   = (const float*)d_in[8];
    const float* vpW   = (const float*)d_in[9];
    const float* qpW   = (const float*)d_in[10];
    const float* rpW   = (const float*)d_in[11];
    const float* rpb   = (const float*)d_in[12];
    const float* outW  = (const float*)d_in[13];
    const float* outb  = (const float*)d_in[14];
    float* out = (float*)d_out;

    float* knv  = (float*)d_ws;
    float* vthr = knv  + (size_t)64 * 1024 * 128;
    float* qbuf = vthr + (size_t)64 * 1024;

    token_kernel<<<2048, 256, 0, stream>>>(seq, embed, ffW1, ffb1, ffW2, ffb2,
                                           lng, lnb, kpW, vpW, qpW,
                                           knv, vthr, qbuf);
    scan_kernel<<<64, 256, 0, stream>>>(knv, vthr, qbuf,
                                        rpW, rpb, outW, outb, out);
}

// Round 9
// 348.793 us; speedup vs baseline: 1.2269x; 1.0526x over previous
//
#include <hip/hip_runtime.h>
#include <hip/hip_bf16.h>
#include <math.h>

// Problem constants (reference: B=64, L=1024, H=64, VOCAB=64)
#define BB 64
#define LL 1024
#define HH 64

typedef float v4f __attribute__((ext_vector_type(4)));
#define F4 __builtin_elementwise_fma

// ---------------------------------------------------------------------------
// Kernel 1: per-token phase (unchanged).
// ---------------------------------------------------------------------------
__global__ __launch_bounds__(256, 1)
void token_kernel(const int* __restrict__ seq,
                  const float* __restrict__ embed_W,
                  const float* __restrict__ ff_W1, const float* __restrict__ ff_b1,
                  const float* __restrict__ ff_W2, const float* __restrict__ ff_b2,
                  const float* __restrict__ ln_g, const float* __restrict__ ln_b,
                  const float* __restrict__ kp_W, const float* __restrict__ vp_W,
                  const float* __restrict__ qp_W,
                  float* __restrict__ knv, float* __restrict__ vthr,
                  float* __restrict__ qbuf)
{
    __shared__ __align__(16) float h_s[32][64];    // 8 KB
    __shared__ __align__(16) float t1_s[32][128];  // 16 KB
    __shared__ __align__(16) float hn_s[32][64];   // 8 KB

    const int tid  = threadIdx.x;
    const int tok0 = blockIdx.x * 32;

    // ---- Stage A: embedding gather into LDS ----
#pragma unroll
    for (int k = 0; k < 8; ++k) {
        int e   = k * 256 + tid;
        int tok = e >> 6, i = e & 63;
        int s   = seq[tok0 + tok];
        h_s[tok][i] = embed_W[s * 64 + i];
    }
    __syncthreads();

    // ---- Stage B: FF1 (64 -> 128, ReLU) ----
    {
        const int j = tid & 127;
        const int g = tid >> 7;
        float w1c[64];
#pragma unroll
        for (int ii = 0; ii < 64; ++ii) w1c[ii] = ff_W1[ii * 128 + j];
        const float b1j = ff_b1[j];
#pragma unroll
        for (int tk = 0; tk < 16; ++tk) {
            const int tok = g * 16 + tk;
            const float4* h4 = (const float4*)h_s[tok];
            float a0 = b1j, a1 = 0.f, a2 = 0.f, a3 = 0.f;
#pragma unroll
            for (int w = 0; w < 16; ++w) {
                float4 hv = h4[w];
                a0 = fmaf(hv.x, w1c[4*w+0], a0);
                a1 = fmaf(hv.y, w1c[4*w+1], a1);
                a2 = fmaf(hv.z, w1c[4*w+2], a2);
                a3 = fmaf(hv.w, w1c[4*w+3], a3);
            }
            t1_s[tok][j] = fmaxf((a0 + a1) + (a2 + a3), 0.f);
        }
    }
    __syncthreads();

    // ---- Stage C: FF2 (128 -> 64) + residual + LayerNorm ----
    {
        const int i  = tid & 63;
        const int w4 = tid >> 6;
        const float b2i = ff_b2[i];
        const float gi  = ln_g[i];
        const float bi  = ln_b[i];
        float accf[8];
#pragma unroll
        for (int tk = 0; tk < 8; ++tk) accf[tk] = b2i;
#pragma unroll
        for (int h = 0; h < 2; ++h) {
            float w2c[64];
#pragma unroll
            for (int jj = 0; jj < 64; ++jj) w2c[jj] = ff_W2[(h*64 + jj) * 64 + i];
#pragma unroll
            for (int tk = 0; tk < 8; ++tk) {
                const int tok = w4 * 8 + tk;
                const float4* t4 = (const float4*)&t1_s[tok][h*64];
                float a0 = 0.f, a1 = 0.f, a2 = 0.f, a3 = 0.f;
#pragma unroll
                for (int w = 0; w < 16; ++w) {
                    float4 tv = t4[w];
                    a0 = fmaf(tv.x, w2c[4*w+0], a0);
                    a1 = fmaf(tv.y, w2c[4*w+1], a1);
                    a2 = fmaf(tv.z, w2c[4*w+2], a2);
                    a3 = fmaf(tv.w, w2c[4*w+3], a3);
                }
                accf[tk] += (a0 + a1) + (a2 + a3);
            }
        }
#pragma unroll
        for (int tk = 0; tk < 8; ++tk) {
            const int tok = w4 * 8 + tk;
            float x = h_s[tok][i] + accf[tk];
            float s = x;
#pragma unroll
            for (int m = 32; m > 0; m >>= 1) s += __shfl_xor(s, m);
            float mu = s * (1.f / 64.f);
            float d  = x - mu;
            float s2 = d * d;
#pragma unroll
            for (int m = 32; m > 0; m >>= 1) s2 += __shfl_xor(s2, m);
            float var = s2 * (1.f / 64.f);
            hn_s[tok][i] = d / sqrtf(var + 1e-5f) * gi + bi;
        }
    }
    __syncthreads();

    // ---- Stage D: kn/v into packed stream (t<1023) OR q (t==1023) ----
    {
        const int i  = tid & 63;
        const int w4 = tid >> 6;
        float kc[64], vc[64];
#pragma unroll
        for (int ii = 0; ii < 64; ++ii) {
            kc[ii] = kp_W[ii * 64 + i];
            vc[ii] = vp_W[ii * 64 + i];
        }
#pragma unroll
        for (int tk = 0; tk < 8; ++tk) {
            const int tok = w4 * 8 + tk;
            const int tg  = tok0 + tok;
            const int b   = tg >> 10;
            const int t   = tg & 1023;
            const float4* hn4 = (const float4*)hn_s[tok];
            if (t < 1023) {
                float ka0=0.f,ka1=0.f,ka2=0.f,ka3=0.f;
                float va0=0.f,va1=0.f,va2=0.f,va3=0.f;
#pragma unroll
                for (int w = 0; w < 16; ++w) {
                    float4 hv = hn4[w];
                    ka0 = fmaf(hv.x, kc[4*w+0], ka0);
                    ka1 = fmaf(hv.y, kc[4*w+1], ka1);
                    ka2 = fmaf(hv.z, kc[4*w+2], ka2);
                    ka3 = fmaf(hv.w, kc[4*w+3], ka3);
                    va0 = fmaf(hv.x, vc[4*w+0], va0);
                    va1 = fmaf(hv.y, vc[4*w+1], va1);
                    va2 = fmaf(hv.z, vc[4*w+2], va2);
                    va3 = fmaf(hv.w, vc[4*w+3], va3);
                }
                float ka = (ka0 + ka1) + (ka2 + ka3);
                float va = (va0 + va1) + (va2 + va3);
                float kn2 = ka * ka, vn2 = va * va;
#pragma unroll
                for (int m = 32; m > 0; m >>= 1) {
                    kn2 += __shfl_xor(kn2, m);
                    vn2 += __shfl_xor(vn2, m);
                }
                float knorm = fmaxf(sqrtf(kn2), 1e-12f);
                size_t row = ((size_t)b * 1024 + t) * 128;
                knv[row + i]      = ka / knorm;
                knv[row + 64 + i] = va;
                if (i == 0) vthr[b * 1024 + t] = 0.16f * vn2;   // SQUARED threshold
            } else {
                float qa0=0.f,qa1=0.f,qa2=0.f,qa3=0.f;
#pragma unroll
                for (int w = 0; w < 16; ++w) {
                    float4 hv = hn4[w];
                    qa0 = fmaf(hv.x, qp_W[(4*w+0)*64 + i], qa0);
                    qa1 = fmaf(hv.y, qp_W[(4*w+1)*64 + i], qa1);
                    qa2 = fmaf(hv.z, qp_W[(4*w+2)*64 + i], qa2);
                    qa3 = fmaf(hv.w, qp_W[(4*w+3)*64 + i], qa3);
                }
                qbuf[b * 64 + i] = (qa0 + qa1) + (qa2 + qa3);
            }
        }
    }
}

// ---------------------------------------------------------------------------
// Kernel 2: sequential fast-weight scan + output head.
// G=4 CHUNKS (one barrier per FOUR steps), 4-wave column split.
//
// Chunk u = steps (a,b,c,d) = (4u..4u+3). Entering: M = M_{4u-5}; gd0..gd3 =
// gated deltas of chunk u-1; banks: U-rows = kn of chunk u-1, D-rows = kn of
// chunk u; c01..c23 = within-chunk kn grams of chunk u (computed last chunk).
//   1. UPD x4 (gd of chunk u-1)                  -> M = M_{4u-1}
//   2. quarter-DOT x4 of D-rows; publish float4; lgkmcnt(0)+barrier
//   3. read 4 partials; fixed tree (p0+p1)+(p2+p3) -> base_i; d_i0 = v_i-base_i
//   4. stage1 reduce (6-way DPP): {d0^2, d0.d1, d1^2} + 3 kn grams
//      gates g0,g1 via e1 = S11 - g0(2 c01 S01 - c01^2 S00)  [exact expansion]
//   5. per-lane exact corrections: d2' = d20 - c02 gd0 - c12 gd1; d3' likewise
//   6. stage2 reduce (6-way): {d2'^2, d2'.d3', d3'^2} + 3 kn grams
//      gates g2,g3 via the same pair expansion with c23
//   7. refill U-rows <- kn of chunk u+1 (becomes next D); rotate scalars
// All gate inputs are computed BIT-IDENTICALLY in all 4 waves (fixed trees,
// redundant reduces) -- divergent gates would fork M. Step 1023 is a dummy
// row; everything derived from it flows only into discarded gd3 (NaN-safe:
// NaN > th is false).
//
// grid = 64 (one block/batch), block = 256 (4 waves). Lane i owns M row i;
// wave w owns columns [16w,16w+16). Staging: wave w stages rows 4w..4w+3 of
// each 16-row buffer (2 x global_load_lds-16B), counted vmcnt(2), 3-slot ring.
// ---------------------------------------------------------------------------

template<int CTRL>
__device__ __forceinline__ float dppadd(float x) {
    int y = __builtin_amdgcn_update_dpp(0, __float_as_int(x), CTRL, 0xF, 0xF, true);
    return x + __int_as_float(y);
}

__device__ __forceinline__ float bcast63(float x) {
    return __int_as_float(__builtin_amdgcn_readlane(__float_as_int(x), 63));
}

// six independent wave sums, DPP levels interleaved (latency amortized)
__device__ __forceinline__ void wsum6(float& a, float& b, float& c,
                                      float& d, float& e, float& f) {
#define LVL(C) a=dppadd<C>(a); b=dppadd<C>(b); c=dppadd<C>(c); \
               d=dppadd<C>(d); e=dppadd<C>(e); f=dppadd<C>(f);
    LVL(0x111) LVL(0x112) LVL(0x114) LVL(0x118) LVL(0x142) LVL(0x143)
#undef LVL
    a=bcast63(a); b=bcast63(b); c=bcast63(c);
    d=bcast63(d); e=bcast63(e); f=bcast63(f);
}

// load this wave's quarter of a kn row into quarter-set P (4 x ds_read_b128)
#define LOADK4(P, ROW) do { \
    const float* r_ = (ROW) + (wid << 4); \
    P##0 = *(const v4f*)(r_ + 0);  P##1 = *(const v4f*)(r_ + 4); \
    P##2 = *(const v4f*)(r_ + 8);  P##3 = *(const v4f*)(r_ + 12); \
} while (0)

// M(quarter) += G * P(quarter)   (branchless; G==0 exact no-op on finite P)
#define UPD4(P, G) do { \
    v4f gv_ = {G, G, G, G}; \
    m0 = F4(gv_, P##0, m0); m1 = F4(gv_, P##1, m1); \
    m2 = F4(gv_, P##2, m2); m3 = F4(gv_, P##3, m3); \
} while (0)

// OUT = quarter dot of M with row P (fixed fold tree, matches round-8)
#define DOT4(P, OUT) do { \
    v4f t_ = F4(m0, P##0, F4(m1, P##1, F4(m2, P##2, m3 * P##3))); \
    OUT = (t_.x + t_.y) + (t_.z + t_.w); \
} while (0)

// One chunk u (steps 4u..4u+3). U0..U3 = UPD rows (chunk u-1, then refilled
// with chunk u+1 rows), D0..D3 = DOT rows (chunk u). R4..R7 / T4..T7 = next
// chunk's packed rows / squared thresholds. PAR = u&1 (pex slot parity).
#define CHUNK4(U0_, U1_, U2_, U3_, D0_, D1_, D2_, D3_, R4, R5, R6, R7, \
               T4, T5, T6, T7, PAR) do { \
    UPD4(U0_, gd0); UPD4(U1_, gd1); UPD4(U2_, gd2); UPD4(U3_, gd3); \
    float o0_, o1_, o2_, o3_; \
    DOT4(D0_, o0_); DOT4(D1_, o1_); DOT4(D2_, o2_); DOT4(D3_, o3_); \
    ((float4*)pex[PAR][wid])[lane] = make_float4(o0_, o1_, o2_, o3_); \
    asm volatile("s_waitcnt lgkmcnt(0)\n\ts_barrier" ::: "memory"); \
    float4 p0_ = ((const float4*)pex[PAR][0])[lane]; \
    float4 p1_ = ((const float4*)pex[PAR][1])[lane]; \
    float4 p2_ = ((const float4*)pex[PAR][2])[lane]; \
    float4 p3_ = ((const float4*)pex[PAR][3])[lane]; \
    float kn4_ = (R4)[lane], kn5_ = (R5)[lane]; \
    float kn6_ = (R6)[lane], kn7_ = (R7)[lane]; \
    float vv4_ = (R4)[64 + lane], vv5_ = (R5)[64 + lane]; \
    float vv6_ = (R6)[64 + lane], vv7_ = (R7)[64 + lane]; \
    float t4_ = *(T4), t5_ = *(T5), t6_ = *(T6), t7_ = *(T7); \
    LOADK4(U0_, R4); LOADK4(U1_, R5); LOADK4(U2_, R6); LOADK4(U3_, R7); \
    float b0_ = (p0_.x + p1_.x) + (p2_.x + p3_.x); \
    float b1_ = (p0_.y + p1_.y) + (p2_.y + p3_.y); \
    float b2_ = (p0_.z + p1_.z) + (p2_.z + p3_.z); \
    float b3_ = (p0_.w + p1_.w) + (p2_.w + p3_.w); \
    float d0_ = vv0 - b0_, d1_ = vv1 - b1_; \
    float d2_ = vv2 - b2_, d3_ = vv3 - b3_; \
    float x0_ = d0_ * d0_, x1_ = d0_ * d1_, x2_ = d1_ * d1_; \
    float x3_ = kn4_ * kn5_, x4_ = kn4_ * kn6_, x5_ = kn4_ * kn7_; \
    wsum6(x0_, x1_, x2_, x3_, x4_, x5_); \
    bool g0_ = x0_ > th0; \
    float co1_ = fmaf(2.f * c01, x1_, -(c01 * c01) * x0_); \
    float e1_ = g0_ ? (x2_ - co1_) : x2_; \
    bool g1_ = e1_ > th1; \
    float gda_ = g0_ ? d0_ : 0.f; \
    float gdb_ = g1_ ? fmaf(-c01, gda_, d1_) : 0.f; \
    float d2p_ = fmaf(-c12, gdb_, fmaf(-c02, gda_, d2_)); \
    float d3p_ = fmaf(-c13, gdb_, fmaf(-c03, gda_, d3_)); \
    float y0_ = d2p_ * d2p_, y1_ = d2p_ * d3p_, y2_ = d3p_ * d3p_; \
    float y3_ = kn5_ * kn6_, y4_ = kn5_ * kn7_, y5_ = kn6_ * kn7_; \
    wsum6(y0_, y1_, y2_, y3_, y4_, y5_); \
    bool g2_ = y0_ > th2; \
    float co2_ = fmaf(2.f * c23, y1_, -(c23 * c23) * y0_); \
    float e3_ = g2_ ? (y2_ - co2_) : y2_; \
    bool g3_ = e3_ > th3; \
    float gdc_ = g2_ ? d2p_ : 0.f; \
    float gdd_ = g3_ ? fmaf(-c23, gdc_, d3p_) : 0.f; \
    gd0 = gda_; gd1 = gdb_; gd2 = gdc_; gd3 = gdd_; \
    c01 = x3_; c02 = x4_; c03 = x5_; c12 = y3_; c13 = y4_; c23 = y5_; \
    vv0 = vv4_; vv1 = vv5_; vv2 = vv6_; vv3 = vv7_; \
    th0 = t4_; th1 = t5_; th2 = t6_; th3 = t7_; \
} while (0)

// 4 chunks covering one 16-row buffer. Bank roles: even chunk -> UPD B, DOT A;
// odd chunk -> UPD A, DOT B. Last chunk's lookahead rows come from NB.
#define BUF4(CB, NB, TP) \
    CHUNK4(B0,B1,B2,B3, A0,A1,A2,A3, (CB)+4*128,(CB)+5*128,(CB)+6*128,(CB)+7*128, \
           (TP)+4,(TP)+5,(TP)+6,(TP)+7, 0); \
    CHUNK4(A0,A1,A2,A3, B0,B1,B2,B3, (CB)+8*128,(CB)+9*128,(CB)+10*128,(CB)+11*128, \
           (TP)+8,(TP)+9,(TP)+10,(TP)+11, 1); \
    CHUNK4(B0,B1,B2,B3, A0,A1,A2,A3, (CB)+12*128,(CB)+13*128,(CB)+14*128,(CB)+15*128, \
           (TP)+12,(TP)+13,(TP)+14,(TP)+15, 0); \
    CHUNK4(A0,A1,A2,A3, B0,B1,B2,B3, (NB)+0*128,(NB)+1*128,(NB)+2*128,(NB)+3*128, \
           (TP)+16,(TP)+17,(TP)+18,(TP)+19, 1);

// async copy: 1024 B contiguous global -> contiguous LDS (one inst)
__device__ __forceinline__ void gl2lds_1k(const float* g, float* l, int lane) {
    __builtin_amdgcn_global_load_lds(
        (const __attribute__((address_space(1))) void*)(g + lane * 4),
        (__attribute__((address_space(3))) void*)l, 16, 0, 0);
}

// wave w stages rows 4w..4w+3 of a 16-row buffer (2 KB = 2 insts)
__device__ __forceinline__ void prefetch_quarter(const float* g, float* l,
                                                 int lane, int wid) {
#pragma unroll
    for (int j = 0; j < 2; ++j)
        gl2lds_1k(g + wid * 512 + j * 256, l + wid * 512 + j * 256, lane);
}

__global__ __launch_bounds__(256, 1)
void scan_kernel(const float* __restrict__ knv,
                 const float* __restrict__ vthr,
                 const float* __restrict__ qbuf,
                 const float* __restrict__ rp_W, const float* __restrict__ rp_b,
                 const float* __restrict__ out_W, const float* __restrict__ out_b,
                 float* __restrict__ out)
{
    const int b    = blockIdx.x;
    const int tid  = threadIdx.x;
    const int lane = tid & 63;
    const int wid  = tid >> 6;
    const float* knvb = knv  + (size_t)b * 1024 * 128;
    const float* thrb = vthr + (size_t)b * 1024;

    __shared__ __align__(16) float thr_s[1040];      // th^2 per step (+peek pad)
    __shared__ __align__(16) float buf[3 * 2048];    // 3 x 8 KB buffers
    __shared__ __align__(16) float pex[2][4][256];   // [parity][wave][lane*4]
    __shared__ float sh[64];

    // M quarter: columns [16*wid, 16*wid+16) of lane's row (4 v4f)
    v4f m0={0,0,0,0}, m1={0,0,0,0}, m2={0,0,0,0}, m3={0,0,0,0};
    // two banks of 4 quarter-row sets (A = even-chunk rows, B = odd-chunk rows)
    v4f A00,A01,A02,A03, A10,A11,A12,A13, A20,A21,A22,A23, A30,A31,A32,A33;
    v4f B00,B01,B02,B03, B10,B11,B12,B13, B20,B21,B22,B23, B30,B31,B32,B33;

    // staging: wave 0 also loads thr (4 insts); each wave 2 insts/buffer
    if (wid == 0) {
#pragma unroll
        for (int w = 0; w < 4; ++w) gl2lds_1k(thrb + w * 256, thr_s + w * 256, lane);
    }
    prefetch_quarter(knvb,        buf,        lane, wid);
    prefetch_quarter(knvb + 2048, buf + 2048, lane, wid);
    prefetch_quarter(knvb + 4096, buf + 4096, lane, wid);

    // thr + buffers 0,1 resident own-wave (buffer 2 = 2 insts in flight);
    // barrier makes all waves' quarters visible.
    asm volatile("s_waitcnt vmcnt(2) lgkmcnt(0)\n\ts_barrier" ::: "memory");

    // prologue: bank A <- rows 0..3 (chunk 0's DOT rows); bank B (plays
    // chunk -1 rows for the gd=0 UPDs) must be finite: zero it.
    LOADK4(A0, buf + 0*128); LOADK4(A1, buf + 1*128);
    LOADK4(A2, buf + 2*128); LOADK4(A3, buf + 3*128);
    {
        v4f z_ = {0.f, 0.f, 0.f, 0.f};
        B00=z_;B01=z_;B02=z_;B03=z_; B10=z_;B11=z_;B12=z_;B13=z_;
        B20=z_;B21=z_;B22=z_;B23=z_; B30=z_;B31=z_;B32=z_;B33=z_;
    }
    float vv0 = buf[0*128+64+lane], vv1 = buf[1*128+64+lane];
    float vv2 = buf[2*128+64+lane], vv3 = buf[3*128+64+lane];
    float th0 = thr_s[0], th1 = thr_s[1], th2 = thr_s[2], th3 = thr_s[3];
    float c01, c02, c03, c12, c13, c23;
    {
        float k0_ = buf[0*128+lane], k1_ = buf[1*128+lane];
        float k2_ = buf[2*128+lane], k3_ = buf[3*128+lane];
        c01 = k0_*k1_; c02 = k0_*k2_; c03 = k0_*k3_;
        c12 = k1_*k2_; c13 = k1_*k3_; c23 = k2_*k3_;
        wsum6(c01, c02, c03, c12, c13, c23);
    }
    float gd0 = 0.f, gd1 = 0.f, gd2 = 0.f, gd3 = 0.f;

#pragma unroll 1
    for (int c = 0; c < 62; ++c) {
        // own outstanding <= 4 (buffers c+1, c+2); vmcnt(2) -> buffer c+1
        // resident own-wave; chunk barriers give cross-wave visibility.
        asm volatile("s_waitcnt vmcnt(2)" ::: "memory");
        const float* cb = buf + (c % 3) * 2048;
        const float* nb = buf + ((c + 1) % 3) * 2048;
        const float* tp = thr_s + c * 16;
        BUF4(cb, nb, tp)
        if (c <= 60)
            prefetch_quarter(knvb + (size_t)(c + 3) * 2048,
                             buf + (c % 3) * 2048, lane, wid);
    }
    asm volatile("s_waitcnt vmcnt(0)" ::: "memory");
    asm volatile("s_barrier" ::: "memory");   // all waves' buffers 62,63 staged
    {   // buffer 62 (slot 2), lookahead into buffer 63 (slot 0)
        const float* cb = buf + 2 * 2048;
        const float* nb = buf;
        const float* tp = thr_s + 62 * 16;
        BUF4(cb, nb, tp)
    }
    {   // buffer 63 (slot 0): steps 1008..1023 (1023 = dummy); NB dummy slot 1.
        // thr peeks hit thr_s[1024..1027] (allocated, garbage, unused).
        const float* cb = buf;
        const float* nb = buf + 2048;
        const float* tp = thr_s + 63 * 16;
        BUF4(cb, nb, tp)
    }
    // epilogue: chunk 255's gates are in gd0..gd3; rows 1020..1022 are in
    // bank B rows 0..2 (row 1023 = garbage, its gd3 is discarded).
    // M_{1022} = M_{1019} + gd_{1020} kn_{1020}^T + gd_{1021} kn_{1021}^T
    //            + gd_{1022} kn_{1022}^T
    UPD4(B0, gd0); UPD4(B1, gd1); UPD4(B2, gd2);

    // ---- output head: vq = M q (quarter + exchange), wave 0 finishes ----
    {
        const v4f* qq = (const v4f*)(qbuf + b * 64);
        const int w4i = 4 * wid;
        v4f aq = F4(m0, qq[w4i+0], F4(m1, qq[w4i+1],
                 F4(m2, qq[w4i+2],  m3 * qq[w4i+3])));
        float vq_own = (aq.x + aq.y) + (aq.z + aq.w);
        pex[0][wid][lane] = vq_own;
        asm volatile("s_waitcnt lgkmcnt(0)\n\ts_barrier" ::: "memory");

        if (wid == 0) {
            float vq = (pex[0][0][lane] + pex[0][1][lane])
                     + (pex[0][2][lane] + pex[0][3][lane]);
            sh[lane] = vq;
            asm volatile("s_waitcnt lgkmcnt(0)" ::: "memory");
            float r = rp_b[lane];
#pragma unroll
            for (int ii = 0; ii < 64; ++ii) r = fmaf(sh[ii], rp_W[ii * 64 + lane], r);
            asm volatile("s_waitcnt lgkmcnt(0)" ::: "memory");
            sh[lane] = r;
            asm volatile("s_waitcnt lgkmcnt(0)" ::: "memory");
            float o = out_b[lane];
#pragma unroll
            for (int ii = 0; ii < 64; ++ii) o = fmaf(sh[ii], out_W[ii * 64 + lane], o);
            out[b * 64 + lane] = o;
        }
    }
}

// ---------------------------------------------------------------------------
// Launch. Workspace (fp32): knv[64][1024][128] (33.55 MB, t=1023 row unused) |
// vthr[64][1024] (262 KB) | qbuf[64][64]. Total ~33.9 MB.
// ---------------------------------------------------------------------------
extern "C" void kernel_launch(void* const* d_in, const int* in_sizes, int n_in,
                              void* d_out, int out_size, void* d_ws, size_t ws_size,
                              hipStream_t stream)
{
    const int*   seq   = (const int*)  d_in[0];
    const float* embed = (const float*)d_in[1];
    const float* ffW1  = (const float*)d_in[2];
    const float* ffb1  = (const float*)d_in[3];
    const float* ffW2  = (const float*)d_in[4];
    const float* ffb2  = (const float*)d_in[5];
    const float* lng   = (const float*)d_in[6];
    const float* lnb   = (const float*)d_in[7];
    const float* kpW   = (const float*)d_in[8];
    const float* vpW   = (const float*)d_in[9];
    const float* qpW   = (const float*)d_in[10];
    const float* rpW   = (const float*)d_in[11];
    const float* rpb   = (const float*)d_in[12];
    const float* outW  = (const float*)d_in[13];
    const float* outb  = (const float*)d_in[14];
    float* out = (float*)d_out;

    float* knv  = (float*)d_ws;
    float* vthr = knv  + (size_t)64 * 1024 * 128;
    float* qbuf = vthr + (size_t)64 * 1024;

    token_kernel<<<2048, 256, 0, stream>>>(seq, embed, ffW1, ffb1, ffW2, ffb2,
                                           lng, lnb, kpW, vpW, qpW,
                                           knv, vthr, qbuf);
    scan_kernel<<<64, 256, 0, stream>>>(knv, vthr, qbuf,
                                        rpW, rpb, outW, outb, out);
}